// Round 3
// baseline (748.724 us; speedup 1.0000x reference)
//
#include <hip/hip_runtime.h>
#include <hip/hip_fp16.h>

#define D 64
#define NKR 16
#define NB 1024
#define NL 8
#define LSTR 72   // Trow padded row stride (elements); 144B = 4-bank rotation/row

typedef __attribute__((ext_vector_type(8))) _Float16 half8;
typedef __attribute__((ext_vector_type(16))) float f32x16;
typedef __attribute__((ext_vector_type(4))) int i32x4;

static __device__ __forceinline__ half8 neg8(half8 x) {
    i32x4 u = __builtin_bit_cast(i32x4, x);
    u = u ^ (int)0x80008000;
    return __builtin_bit_cast(half8, u);
}

union Pack4 { _Float16 h[4]; uint2 u; };

#define GLDS16(gp, lp) \
    __builtin_amdgcn_global_load_lds((const __attribute__((address_space(1))) void*)(gp), \
                                     (__attribute__((address_space(3))) void*)(lp), 16, 0, 0)

// kraus fp32 -> fp16, layout [L][K][2][64][64] with XOR-swizzled 16B granules:
// element (plane,row,col) -> plane*4096 + row*64 + ((col>>3)^(row&7))*8 + (col&7)
__global__ void kconv_kernel(const float* __restrict__ re, const float* __restrict__ im,
                             _Float16* __restrict__ out) {
    int plane = blockIdx.y;
    int idx = blockIdx.x * blockDim.x + threadIdx.x;
    const float* src = plane ? im : re;
    float4 v = ((const float4*)src)[idx];
    int e = idx * 4;
    int lk = e >> 12;
    int rem = e & 4095;
    int row = rem >> 6, col = rem & 63;          // col multiple of 4 -> stays in one granule
    int grp = (col >> 3) ^ (row & 7);
    Pack4 p;
    p.h[0] = (_Float16)v.x; p.h[1] = (_Float16)v.y;
    p.h[2] = (_Float16)v.z; p.h[3] = (_Float16)v.w;
    *(uint2*)(out + ((size_t)lk * 2 + plane) * 4096 + row * 64 + grp * 8 + (col & 7)) = p.u;
}

// state fp32 -> fp16 transposed: out[b][plane][l][j] = state[b][j][l]
__global__ void sconv_kernel(const float* __restrict__ re, const float* __restrict__ im,
                             _Float16* __restrict__ out) {
    __shared__ float tile[64][65];
    int b = blockIdx.x;
    int t = threadIdx.x;
    for (int plane = 0; plane < 2; ++plane) {
        const float* src = (plane ? im : re) + (size_t)b * 4096;
        __syncthreads();
        #pragma unroll
        for (int i = 0; i < 16; ++i) {
            int e = t + 256 * i;
            tile[e >> 6][e & 63] = src[e];
        }
        __syncthreads();
        _Float16* o = out + ((size_t)b * 2 + plane) * 4096;
        #pragma unroll
        for (int i = 0; i < 16; ++i) {
            int e = t + 256 * i;            // e = l*64 + j
            o[e] = (_Float16)tile[e & 63][e >> 6];
        }
    }
}

// One block per b; 4 waves; wave (wr,wc) owns a 32x32 tile.
// Per kraus k: stage1 Tt = rho^T*K^T (A1 hoisted regs, B from swizzled Klds, cached in
// regs), Trow round-trip; async global_load_lds of K_{k+1} overlaps stage2 MFMAs.
__global__ __launch_bounds__(256, 4) void layer_kernel(
    const _Float16* __restrict__ rho_in,
    _Float16* __restrict__ rho_out,
    float* __restrict__ final_out,
    const _Float16* __restrict__ kraus,   // this layer, swizzled: [K][2][64][64]
    int last)
{
    __shared__ __align__(16) _Float16 Klds[2 * D * D];        // 16 KB, linear+swizzled
    __shared__ __align__(16) _Float16 Trow[2][D][LSTR];       // 18 KB, padded

    const int b    = blockIdx.x;
    const int t    = threadIdx.x;
    const int wv   = t >> 6;
    const int lane = t & 63;
    const int l31  = lane & 31;
    const int hl   = lane >> 5;
    const int wr   = wv >> 1;
    const int wc   = wv & 1;

    // ---- hoisted A1 fragments: rho^T row l = 32*wr + l31 ----
    half8 a1re[4], a1im[4];
    {
        const _Float16* rb = rho_in + (size_t)b * 2 * D * D;
        const int row = 32 * wr + l31;
        #pragma unroll
        for (int ks = 0; ks < 4; ++ks) {
            const int col = 16 * ks + 8 * hl;
            a1re[ks] = *(const half8*)(rb + row * D + col);
            a1im[ks] = *(const half8*)(rb + D * D + row * D + col);
        }
    }

    // ---- preload K_0 into LDS (async, drained by barrier) ----
    {
        const char* kb = (const char*)kraus;
        const int off = wv * 4096;                 // bytes; each wave fills 4 KB
        #pragma unroll
        for (int r = 0; r < 4; ++r)
            GLDS16(kb + off + r * 1024 + lane * 16, (char*)Klds + off + r * 1024);
    }

    f32x16 accRe, accIm;
    #pragma unroll
    for (int i = 0; i < 16; ++i) { accRe[i] = 0.f; accIm[i] = 0.f; }

    __syncthreads();

    // swizzled B-read base: row1 = 32*wc + l31, granule grp = (2ks+hl) ^ (row1&7)
    const int row1  = 32 * wc + l31;
    const int rb1   = row1 * 64;
    const int rx1   = row1 & 7;

    #pragma unroll 1
    for (int k = 0; k < NKR; ++k) {
        // ---- stage 1: two passes (d_re then d_im), cache B fragments ----
        half8 bre[4], bim[4];
        f32x16 dd;
        #pragma unroll
        for (int i = 0; i < 16; ++i) dd[i] = 0.f;
        #pragma unroll
        for (int ks = 0; ks < 4; ++ks) {
            const int g = ((2 * ks + hl) ^ rx1) * 8;
            bre[ks] = *(const half8*)&Klds[rb1 + g];
            bim[ks] = *(const half8*)&Klds[4096 + rb1 + g];
            dd = __builtin_amdgcn_mfma_f32_32x32x16_f16(a1re[ks], bre[ks],       dd, 0, 0, 0);
            dd = __builtin_amdgcn_mfma_f32_32x32x16_f16(a1im[ks], neg8(bim[ks]), dd, 0, 0, 0);
        }
        {   // D1: col i = 32wc+l31; reg 4g+j -> row l = 32wr + 8g + 4hl + j
            const int i = 32 * wc + l31;
            #pragma unroll
            for (int g = 0; g < 4; ++g) {
                Pack4 pr;
                #pragma unroll
                for (int j = 0; j < 4; ++j) pr.h[j] = (_Float16)dd[4 * g + j];
                *(uint2*)&Trow[0][i][32 * wr + 8 * g + 4 * hl] = pr.u;
            }
        }
        #pragma unroll
        for (int i = 0; i < 16; ++i) dd[i] = 0.f;
        #pragma unroll
        for (int ks = 0; ks < 4; ++ks) {
            dd = __builtin_amdgcn_mfma_f32_32x32x16_f16(a1re[ks], bim[ks], dd, 0, 0, 0);
            dd = __builtin_amdgcn_mfma_f32_32x32x16_f16(a1im[ks], bre[ks], dd, 0, 0, 0);
        }
        {
            const int i = 32 * wc + l31;
            #pragma unroll
            for (int g = 0; g < 4; ++g) {
                Pack4 pi;
                #pragma unroll
                for (int j = 0; j < 4; ++j) pi.h[j] = (_Float16)dd[4 * g + j];
                *(uint2*)&Trow[1][i][32 * wr + 8 * g + 4 * hl] = pi.u;
            }
        }
        __syncthreads();   // Klds reads + Trow writes complete

        // ---- async stage K_{k+1}: flies during stage2, drained at end barrier ----
        if (k + 1 < NKR) {
            const char* kb = (const char*)(kraus + (size_t)(k + 1) * 2 * D * D);
            const int off = wv * 4096;
            #pragma unroll
            for (int r = 0; r < 4; ++r)
                GLDS16(kb + off + r * 1024 + lane * 16, (char*)Klds + off + r * 1024);
        }

        // ---- stage 2: rho_new += T * K^dagger (B fragments reused from regs) ----
        #pragma unroll
        for (int ks = 0; ks < 4; ++ks) {
            const int lcol = 16 * ks + 8 * hl;
            half8 are = *(const half8*)&Trow[0][32 * wr + l31][lcol];
            half8 aim = *(const half8*)&Trow[1][32 * wr + l31][lcol];
            accRe = __builtin_amdgcn_mfma_f32_32x32x16_f16(are, bre[ks],       accRe, 0, 0, 0);
            accRe = __builtin_amdgcn_mfma_f32_32x32x16_f16(aim, bim[ks],       accRe, 0, 0, 0);
            accIm = __builtin_amdgcn_mfma_f32_32x32x16_f16(aim, bre[ks],       accIm, 0, 0, 0);
            accIm = __builtin_amdgcn_mfma_f32_32x32x16_f16(are, neg8(bim[ks]), accIm, 0, 0, 0);
        }
        __syncthreads();   // Trow reads done; K_{k+1} staging drained (vmcnt(0))
    }

    // ---- epilogue: col m = 32wc+l31; reg 4g+j -> row i = 32wr + 8g + 4hl + j ----
    if (!last) {
        _Float16* ob = rho_out + (size_t)b * 2 * D * D;
        const int m = 32 * wc + l31;
        #pragma unroll
        for (int g = 0; g < 4; ++g) {
            Pack4 pr, pi;
            #pragma unroll
            for (int j = 0; j < 4; ++j) {
                pr.h[j] = (_Float16)accRe[4 * g + j];
                pi.h[j] = (_Float16)accIm[4 * g + j];
            }
            const int i0 = 32 * wr + 8 * g + 4 * hl;
            *(uint2*)(ob + m * D + i0)         = pr.u;   // rho_new^T[m][i]
            *(uint2*)(ob + D * D + m * D + i0) = pi.u;
        }
    } else {
        float* o0 = final_out + (size_t)b * 4096;            // [0][b][i][m]
        float* o1 = final_out + (size_t)(NB + b) * 4096;     // [1][b][i][m]
        const int m = 32 * wc + l31;
        #pragma unroll
        for (int g = 0; g < 4; ++g) {
            #pragma unroll
            for (int j = 0; j < 4; ++j) {
                const int i = 32 * wr + 8 * g + 4 * hl + j;
                o0[i * D + m] = accRe[4 * g + j];
                o1[i * D + m] = accIm[4 * g + j];
            }
        }
    }
}

extern "C" void kernel_launch(void* const* d_in, const int* in_sizes, int n_in,
                              void* d_out, int out_size, void* d_ws, size_t ws_size,
                              hipStream_t stream) {
    const float* state_re = (const float*)d_in[0];
    const float* state_im = (const float*)d_in[1];
    const float* kraus_re = (const float*)d_in[2];
    const float* kraus_im = (const float*)d_in[3];

    _Float16* kraus_h = (_Float16*)d_ws;                         // 2 MB in ws (swizzled)
    _Float16* bufA = (_Float16*)d_out;
    _Float16* bufB = (_Float16*)((char*)d_out + (size_t)NB * 2 * D * D * sizeof(_Float16));
    float* fout = (float*)d_out;

    kconv_kernel<<<dim3(512, 2), 256, 0, stream>>>(kraus_re, kraus_im, kraus_h);
    sconv_kernel<<<NB, 256, 0, stream>>>(state_re, state_im, bufA);

    for (int l = 0; l < NL; ++l) {
        const _Float16* in = (l & 1) ? bufB : bufA;
        _Float16* out      = (l & 1) ? bufA : bufB;
        layer_kernel<<<NB, 256, 0, stream>>>(in, out, fout,
                                             kraus_h + (size_t)l * NKR * 2 * D * D,
                                             (l == NL - 1) ? 1 : 0);
    }
}

// Round 4
// 556.054 us; speedup vs baseline: 1.3465x; 1.3465x over previous
//
#include <hip/hip_runtime.h>
#include <hip/hip_fp16.h>

#define D 64
#define NKR 16
#define NB 1024
#define NL 8

typedef __attribute__((ext_vector_type(8))) _Float16 half8;
typedef __attribute__((ext_vector_type(16))) float f32x16;
typedef __attribute__((ext_vector_type(4))) int i32x4;

static __device__ __forceinline__ half8 neg8(half8 x) {
    i32x4 u = __builtin_bit_cast(i32x4, x);
    u = u ^ (int)0x80008000;
    return __builtin_bit_cast(half8, u);
}

union Pack4 { _Float16 h[4]; uint2 u; };

#define GLDS16(gp, lp) \
    __builtin_amdgcn_global_load_lds((const __attribute__((address_space(1))) void*)(gp), \
                                     (__attribute__((address_space(3))) void*)(lp), 16, 0, 0)

// kraus fp32 -> fp16, layout [L][K][2][64][64] with XOR-swizzled 16B granules:
// element (plane,row,col) -> plane*4096 + row*64 + ((col>>3)^(row&7))*8 + (col&7)
__global__ void kconv_kernel(const float* __restrict__ re, const float* __restrict__ im,
                             _Float16* __restrict__ out) {
    int plane = blockIdx.y;
    int idx = blockIdx.x * blockDim.x + threadIdx.x;
    const float* src = plane ? im : re;
    float4 v = ((const float4*)src)[idx];
    int e = idx * 4;
    int lk = e >> 12;
    int rem = e & 4095;
    int row = rem >> 6, col = rem & 63;          // col multiple of 4 -> stays in one granule
    int grp = (col >> 3) ^ (row & 7);
    Pack4 p;
    p.h[0] = (_Float16)v.x; p.h[1] = (_Float16)v.y;
    p.h[2] = (_Float16)v.z; p.h[3] = (_Float16)v.w;
    *(uint2*)(out + ((size_t)lk * 2 + plane) * 4096 + row * 64 + grp * 8 + (col & 7)) = p.u;
}

// state fp32 -> fp16 transposed: out[b][plane][l][j] = state[b][j][l]
__global__ void sconv_kernel(const float* __restrict__ re, const float* __restrict__ im,
                             _Float16* __restrict__ out) {
    __shared__ float tile[64][65];
    int b = blockIdx.x;
    int t = threadIdx.x;
    for (int plane = 0; plane < 2; ++plane) {
        const float* src = (plane ? im : re) + (size_t)b * 4096;
        __syncthreads();
        #pragma unroll
        for (int i = 0; i < 16; ++i) {
            int e = t + 256 * i;
            tile[e >> 6][e & 63] = src[e];
        }
        __syncthreads();
        _Float16* o = out + ((size_t)b * 2 + plane) * 4096;
        #pragma unroll
        for (int i = 0; i < 16; ++i) {
            int e = t + 256 * i;            // e = l*64 + j
            o[e] = (_Float16)tile[e & 63][e >> 6];
        }
    }
}

// One block per 2 rho (b0 = 2*blockIdx.x); 4 waves; wave (wr,wc) owns a 32x32 tile of
// both rho. B fragments (K_k) are read from LDS once per wave and reused for both rho
// and both stages (reg-cached). Trow is XOR-swizzled (conflict-free b128 reads).
// Async global_load_lds prefetch of K_{k+1} issued after the mid barrier overlaps
// stage2 MFMAs; drained by the end barrier's vmcnt(0). 2 barriers per kraus.
__global__ __launch_bounds__(256, 2) void layer_kernel(
    const _Float16* __restrict__ rho_in,
    _Float16* __restrict__ rho_out,
    float* __restrict__ final_out,
    const _Float16* __restrict__ kraus,   // this layer, swizzled: [K][2][64][64]
    int last)
{
    __shared__ __align__(16) _Float16 Klds[2 * D * D];        // 16 KB, swizzled
    __shared__ __align__(16) _Float16 Trow[2][2][D * D];      // 32 KB, [rho][plane], swizzled

    const int b0   = blockIdx.x * 2;
    const int t    = threadIdx.x;
    const int wv   = t >> 6;
    const int lane = t & 63;
    const int l31  = lane & 31;
    const int hl   = lane >> 5;
    const int wr   = wv >> 1;
    const int wc   = wv & 1;

    // ---- hoisted A1 fragments for both rho: rho^T row l = 32*wr + l31 ----
    half8 a1re[2][4], a1im[2][4];
    #pragma unroll
    for (int r = 0; r < 2; ++r) {
        const _Float16* rb = rho_in + (size_t)(b0 + r) * 2 * D * D;
        const int row = 32 * wr + l31;
        #pragma unroll
        for (int ks = 0; ks < 4; ++ks) {
            const int col = 16 * ks + 8 * hl;
            a1re[r][ks] = *(const half8*)(rb + row * D + col);
            a1im[r][ks] = *(const half8*)(rb + D * D + row * D + col);
        }
    }

    // ---- preload K_0 into LDS (async, drained by barrier) ----
    {
        const char* kb = (const char*)kraus;
        const int off = wv * 4096;                 // bytes; each wave fills 4 KB
        #pragma unroll
        for (int rr = 0; rr < 4; ++rr)
            GLDS16(kb + off + rr * 1024 + lane * 16, (char*)Klds + off + rr * 1024);
    }

    f32x16 accRe[2], accIm[2];
    #pragma unroll
    for (int r = 0; r < 2; ++r)
        #pragma unroll
        for (int i = 0; i < 16; ++i) { accRe[r][i] = 0.f; accIm[r][i] = 0.f; }

    __syncthreads();

    const int row1 = 32 * wc + l31;       // B row (stage1: i, stage2: m)
    const int rb1  = row1 * 64;
    const int rx1  = row1 & 7;
    const int iS1  = 32 * wc + l31;       // stage1 D column
    const int x1   = iS1 & 7;
    const int iS2  = 32 * wr + l31;       // stage2 A row
    const int x2   = iS2 & 7;

    #pragma unroll 1
    for (int k = 0; k < NKR; ++k) {
        // ---- B fragments from swizzled Klds; cached for both stages ----
        half8 bre[4], bim[4], bimn[4];
        #pragma unroll
        for (int ks = 0; ks < 4; ++ks) {
            const int g = ((2 * ks + hl) ^ rx1) * 8;
            bre[ks]  = *(const half8*)&Klds[rb1 + g];
            bim[ks]  = *(const half8*)&Klds[4096 + rb1 + g];
            bimn[ks] = neg8(bim[ks]);
        }

        // ---- stage 1: Tt = rho^T * K^T, 4 passes (rho x re/im) reusing dd ----
        #pragma unroll
        for (int r = 0; r < 2; ++r) {
            f32x16 dd;
            #pragma unroll
            for (int i = 0; i < 16; ++i) dd[i] = 0.f;
            #pragma unroll
            for (int ks = 0; ks < 4; ++ks) {
                dd = __builtin_amdgcn_mfma_f32_32x32x16_f16(a1re[r][ks], bre[ks],  dd, 0, 0, 0);
                dd = __builtin_amdgcn_mfma_f32_32x32x16_f16(a1im[r][ks], bimn[ks], dd, 0, 0, 0);
            }
            #pragma unroll
            for (int g = 0; g < 4; ++g) {        // row l0 = 32wr + 8g + 4hl, col iS1
                Pack4 pr;
                #pragma unroll
                for (int j = 0; j < 4; ++j) pr.h[j] = (_Float16)dd[4 * g + j];
                *(uint2*)&Trow[r][0][iS1 * 64 + (((4 * wr + g) ^ x1) * 8) + 4 * hl] = pr.u;
            }
            #pragma unroll
            for (int i = 0; i < 16; ++i) dd[i] = 0.f;
            #pragma unroll
            for (int ks = 0; ks < 4; ++ks) {
                dd = __builtin_amdgcn_mfma_f32_32x32x16_f16(a1re[r][ks], bim[ks], dd, 0, 0, 0);
                dd = __builtin_amdgcn_mfma_f32_32x32x16_f16(a1im[r][ks], bre[ks], dd, 0, 0, 0);
            }
            #pragma unroll
            for (int g = 0; g < 4; ++g) {
                Pack4 pi;
                #pragma unroll
                for (int j = 0; j < 4; ++j) pi.h[j] = (_Float16)dd[4 * g + j];
                *(uint2*)&Trow[r][1][iS1 * 64 + (((4 * wr + g) ^ x1) * 8) + 4 * hl] = pi.u;
            }
        }
        __syncthreads();   // Trow writes visible; all Klds reads complete

        // ---- async prefetch K_{k+1} into Klds (stage2 doesn't touch Klds) ----
        if (k + 1 < NKR) {
            const char* kb = (const char*)(kraus + (size_t)(k + 1) * 2 * D * D);
            const int off = wv * 4096;
            #pragma unroll
            for (int rr = 0; rr < 4; ++rr)
                GLDS16(kb + off + rr * 1024 + lane * 16, (char*)Klds + off + rr * 1024);
        }

        // ---- stage 2: rho_new += T * K^dagger (B from regs, A from swizzled Trow) ----
        #pragma unroll
        for (int ks = 0; ks < 4; ++ks) {
            const int lcol = 16 * ks + 8 * hl;
            const int toff = iS2 * 64 + (((lcol >> 3) ^ x2) * 8);
            #pragma unroll
            for (int r = 0; r < 2; ++r) {
                half8 are = *(const half8*)&Trow[r][0][toff];
                half8 aim = *(const half8*)&Trow[r][1][toff];
                accRe[r] = __builtin_amdgcn_mfma_f32_32x32x16_f16(are, bre[ks],  accRe[r], 0, 0, 0);
                accRe[r] = __builtin_amdgcn_mfma_f32_32x32x16_f16(aim, bim[ks],  accRe[r], 0, 0, 0);
                accIm[r] = __builtin_amdgcn_mfma_f32_32x32x16_f16(aim, bre[ks],  accIm[r], 0, 0, 0);
                accIm[r] = __builtin_amdgcn_mfma_f32_32x32x16_f16(are, bimn[ks], accIm[r], 0, 0, 0);
            }
        }
        __syncthreads();   // Trow reads done; prefetch drained (vmcnt(0) at barrier)
    }

    // ---- epilogue: col m = 32wc+l31; reg 4g+j -> row i = 32wr + 8g + 4hl + j ----
    const int m = 32 * wc + l31;
    if (!last) {
        #pragma unroll
        for (int r = 0; r < 2; ++r) {
            _Float16* ob = rho_out + (size_t)(b0 + r) * 2 * D * D;
            #pragma unroll
            for (int g = 0; g < 4; ++g) {
                Pack4 pr, pi;
                #pragma unroll
                for (int j = 0; j < 4; ++j) {
                    pr.h[j] = (_Float16)accRe[r][4 * g + j];
                    pi.h[j] = (_Float16)accIm[r][4 * g + j];
                }
                const int i0 = 32 * wr + 8 * g + 4 * hl;
                *(uint2*)(ob + m * D + i0)         = pr.u;   // rho_new^T[m][i]
                *(uint2*)(ob + D * D + m * D + i0) = pi.u;
            }
        }
    } else {
        #pragma unroll
        for (int r = 0; r < 2; ++r) {
            float* o0 = final_out + (size_t)(b0 + r) * 4096;            // [0][b][i][m]
            float* o1 = final_out + (size_t)(NB + b0 + r) * 4096;       // [1][b][i][m]
            #pragma unroll
            for (int g = 0; g < 4; ++g) {
                #pragma unroll
                for (int j = 0; j < 4; ++j) {
                    const int i = 32 * wr + 8 * g + 4 * hl + j;
                    o0[i * D + m] = accRe[r][4 * g + j];
                    o1[i * D + m] = accIm[r][4 * g + j];
                }
            }
        }
    }
}

extern "C" void kernel_launch(void* const* d_in, const int* in_sizes, int n_in,
                              void* d_out, int out_size, void* d_ws, size_t ws_size,
                              hipStream_t stream) {
    const float* state_re = (const float*)d_in[0];
    const float* state_im = (const float*)d_in[1];
    const float* kraus_re = (const float*)d_in[2];
    const float* kraus_im = (const float*)d_in[3];

    _Float16* kraus_h = (_Float16*)d_ws;                         // 2 MB in ws (swizzled)
    // ping-pong rho buffers live inside d_out (2 x 16 MB = out_size exactly).
    _Float16* bufA = (_Float16*)d_out;
    _Float16* bufB = (_Float16*)((char*)d_out + (size_t)NB * 2 * D * D * sizeof(_Float16));
    float* fout = (float*)d_out;

    kconv_kernel<<<dim3(512, 2), 256, 0, stream>>>(kraus_re, kraus_im, kraus_h);
    sconv_kernel<<<NB, 256, 0, stream>>>(state_re, state_im, bufA);

    for (int l = 0; l < NL; ++l) {
        const _Float16* in = (l & 1) ? bufB : bufA;
        _Float16* out      = (l & 1) ? bufA : bufB;
        layer_kernel<<<NB / 2, 256, 0, stream>>>(in, out, fout,
                                                 kraus_h + (size_t)l * NKR * 2 * D * D,
                                                 (l == NL - 1) ? 1 : 0);
    }
}